// Round 3
// baseline (641.553 us; speedup 1.0000x reference)
//
#include <hip/hip_runtime.h>
#include <cstddef>
#include <cstdint>

#define NB 64
#define ND 1024
#define NO 31
#define NSTEPS 16
#define KS 62            // k-splits (k-chunk = 512 k-units, never crosses an opcode)
#define KT32 992         // total K32 steps = 31*1024/32
#define KC32 16          // K32 steps per block

typedef _Float16 half8 __attribute__((ext_vector_type(8)));
typedef float floatx4 __attribute__((ext_vector_type(4)));

// ---------------- softmax over opcode logits: W[b][t][o] ----------------
__global__ void softmax_k(const float* __restrict__ logits, float* __restrict__ W) {
    int row = blockIdx.x * blockDim.x + threadIdx.x;  // row = b*16 + t
    if (row >= NB * NSTEPS) return;
    const float* x = logits + (size_t)row * NO;
    float m = -1e30f;
    for (int o = 0; o < NO; ++o) m = fmaxf(m, x[o]);
    float e[NO]; float s = 0.f;
    for (int o = 0; o < NO; ++o) { e[o] = expf(x[o] - m); s += e[o]; }
    float inv = 1.0f / s;
    float* wo = W + (size_t)row * NO;
    for (int o = 0; o < NO; ++o) wo[o] = e[o] * inv;
}

// ---- kconv: Ktf fragment-ordered fp16 B ----
// half8 unit index: (ns*KT32 + kt)*64 + l ; element j of that half8 =
//   B[k][n] with k = kt*32 + (l>>4)*8 + j, n = ns*16 + (l&15),
//   B[k][n] = K[o = k>>10][d = k&1023][n]
__global__ void kconv_k(const float* __restrict__ K, _Float16* __restrict__ Ktf) {
    int gid = blockIdx.x * 256 + threadIdx.x;   // total = 64*992*64 = 4,063,232
    int l  = gid & 63;
    int kt = (gid >> 6) % KT32;
    int ns = gid / (64 * KT32);
    int kbase = kt * 32 + (l >> 4) * 8;         // o constant across the 8 j's
    int n  = ns * 16 + (l & 15);
    int o  = kbase >> 10;
    int d0 = kbase & 1023;
    const float* src = K + ((size_t)o << 20) + (size_t)d0 * ND + n;
    half8 v;
    #pragma unroll
    for (int j = 0; j < 8; ++j) v[j] = (_Float16)src[(size_t)j * ND];
    *(half8*)(Ktf + (size_t)gid * 8) = v;
}

// ---- GEMM: P[ks][b][n] = sum over block's k-chunk of (w*h) @ B ----
// grid (8 n-tiles of 128, 62 k-splits), 256 thr. Wave = M64 x N32.
// Full-depth B prefetch into registers (32 b128 loads in flight) issued
// BEFORE A-staging so L3 latency overlaps the stage+barrier.
__global__ __launch_bounds__(256) void gemm_k(
    const float* __restrict__ h, const _Float16* __restrict__ Ktf,
    const float* __restrict__ W, float* __restrict__ P, int step)
{
    __shared__ _Float16 lds_a[64 * 512];   // half8-index: p*64 + b  (p = s*4+q)
    int nb = blockIdx.x;                   // 0..7
    int ks = blockIdx.y;                   // 0..61
    int tid = threadIdx.x;
    int l = tid & 63, w = tid >> 6;
    int o = ks >> 1;
    int d_base = (ks & 1) * 512;

    int ml = l & 15, q = l >> 4;
    int ns0 = nb * 8 + w * 2;                 // two n-subtiles of 16 per wave
    const half8* Bp0 = (const half8*)Ktf + ((size_t)ns0 * KT32 + (size_t)ks * KC32) * 64 + l;
    const half8* Bp1 = (const half8*)Ktf + ((size_t)(ns0 + 1) * KT32 + (size_t)ks * KC32) * 64 + l;

    // ---- issue ALL B loads up front (32 global b128 per lane-pairset) ----
    half8 br0[KC32], br1[KC32];
    #pragma unroll
    for (int s = 0; s < KC32; ++s) br0[s] = Bp0[(size_t)s * 64];
    #pragma unroll
    for (int s = 0; s < KC32; ++s) br1[s] = Bp1[(size_t)s * 64];

    // ---- stage A: fp32 h * w  ->  fp16, frag-ordered (overlaps B latency) ----
    {
        int b = tid >> 2, u = tid & 3;
        float wv = W[((size_t)b * NSTEPS + step) * NO + o];
        const float* hb = h + (size_t)b * ND + d_base;
        #pragma unroll
        for (int li = 0; li < 16; ++li) {
            int p = li * 4 + u;                       // p = s*4+q, d offset = p*8
            float4 x0 = *(const float4*)(hb + p * 8);
            float4 x1 = *(const float4*)(hb + p * 8 + 4);
            half8 v;
            v[0] = (_Float16)(x0.x * wv); v[1] = (_Float16)(x0.y * wv);
            v[2] = (_Float16)(x0.z * wv); v[3] = (_Float16)(x0.w * wv);
            v[4] = (_Float16)(x1.x * wv); v[5] = (_Float16)(x1.y * wv);
            v[6] = (_Float16)(x1.z * wv); v[7] = (_Float16)(x1.w * wv);
            *(half8*)&lds_a[(size_t)(p * 64 + b) * 8] = v;
        }
    }
    __syncthreads();

    const half8* Ap = (const half8*)lds_a;
    floatx4 acc[2][4] = {};
    #pragma unroll
    for (int s = 0; s < KC32; ++s) {
        int abase = (s * 4 + q) * 64 + ml;
        half8 a0 = Ap[abase];
        half8 a1 = Ap[abase + 16];
        half8 a2 = Ap[abase + 32];
        half8 a3 = Ap[abase + 48];
        half8 b0 = br0[s];
        half8 b1 = br1[s];
        acc[0][0] = __builtin_amdgcn_mfma_f32_16x16x32_f16(a0, b0, acc[0][0], 0, 0, 0);
        acc[0][1] = __builtin_amdgcn_mfma_f32_16x16x32_f16(a1, b0, acc[0][1], 0, 0, 0);
        acc[0][2] = __builtin_amdgcn_mfma_f32_16x16x32_f16(a2, b0, acc[0][2], 0, 0, 0);
        acc[0][3] = __builtin_amdgcn_mfma_f32_16x16x32_f16(a3, b0, acc[0][3], 0, 0, 0);
        acc[1][0] = __builtin_amdgcn_mfma_f32_16x16x32_f16(a0, b1, acc[1][0], 0, 0, 0);
        acc[1][1] = __builtin_amdgcn_mfma_f32_16x16x32_f16(a1, b1, acc[1][1], 0, 0, 0);
        acc[1][2] = __builtin_amdgcn_mfma_f32_16x16x32_f16(a2, b1, acc[1][2], 0, 0, 0);
        acc[1][3] = __builtin_amdgcn_mfma_f32_16x16x32_f16(a3, b1, acc[1][3], 0, 0, 0);
    }

    // ---- epilogue: C/D col = l&15, row = (l>>4)*4 + r (verified mapping) ----
    float* Pks = P + (size_t)ks * (NB * ND);
    #pragma unroll
    for (int nsub = 0; nsub < 2; ++nsub) {
        int n = (ns0 + nsub) * 16 + ml;
        #pragma unroll
        for (int mt = 0; mt < 4; ++mt) {
            #pragma unroll
            for (int r = 0; r < 4; ++r) {
                int b = mt * 16 + q * 4 + r;
                Pks[(size_t)b * ND + n] = acc[nsub][mt][r];
            }
        }
    }
}

// ---- reduce KS partials + gated update (float4 per thread) ----
__global__ void update_k(const float* __restrict__ hin, const float* __restrict__ P,
                         const float* __restrict__ operands, float* __restrict__ hout,
                         int step)
{
    int idx = blockIdx.x * blockDim.x + threadIdx.x;   // 16384 threads, float4 each
    int b = idx >> 8, n4 = (idx & 255) * 4;
    float gl = operands[((size_t)b * NSTEPS + step) * 4 + 3];
    float g  = 1.0f / (1.0f + expf(-gl));
    const float* p = P + (size_t)b * ND + n4;
    float sx = 0.f, sy = 0.f, sz = 0.f, sw = 0.f;
    #pragma unroll 2
    for (int ks = 0; ks < KS; ++ks) {
        float4 v = *(const float4*)(p + (size_t)ks * (NB * ND));
        sx += v.x; sy += v.y; sz += v.z; sw += v.w;
    }
    const float* hb = hin + (size_t)b * ND + n4;
    float4 hv = *(const float4*)hb;
    float4 outv;
    outv.x = g * sx + (1.f - g) * hv.x;
    outv.y = g * sy + (1.f - g) * hv.y;
    outv.z = g * sz + (1.f - g) * hv.z;
    outv.w = g * sw + (1.f - g) * hv.w;
    *(float4*)(hout + (size_t)b * ND + n4) = outv;
}

extern "C" void kernel_launch(void* const* d_in, const int* in_sizes, int n_in,
                              void* d_out, int out_size, void* d_ws, size_t ws_size,
                              hipStream_t stream)
{
    const float* logits   = (const float*)d_in[0];  // (64,16,31)
    const float* operands = (const float*)d_in[1];  // (64,16,4)
    const float* signal   = (const float*)d_in[2];  // (64,1024)
    const float* opk      = (const float*)d_in[3];  // (31,1024,1024)
    float* out = (float*)d_out;
    char* ws = (char*)d_ws;

    size_t offW = 0;                                   // 128 KB
    size_t offP = 131072;                              // KS*64*1024*4 = 15.5 MB
    size_t offH = offP + (size_t)KS * NB * ND * 4;
    size_t offK = offH + 2ull * NB * ND * 4;           // Ktf: 62 MB fp16

    float*    W  = (float*)(ws + offW);
    float*    P  = (float*)(ws + offP);
    float*    h0 = (float*)(ws + offH);
    float*    h1 = h0 + NB * ND;
    _Float16* Ktf = (_Float16*)(ws + offK);

    softmax_k<<<dim3(4), 256, 0, stream>>>(logits, W);
    kconv_k<<<dim3(15872), 256, 0, stream>>>(opk, Ktf);

    const float* hc = signal;
    float* hn = h0;
    for (int t = 0; t < NSTEPS; ++t) {
        gemm_k<<<dim3(8, KS), 256, 0, stream>>>(hc, Ktf, W, P, t);
        float* dst = (t == NSTEPS - 1) ? out : hn;
        update_k<<<dim3(64), 256, 0, stream>>>(hc, P, operands, dst, t);
        hc = dst;
        hn = (hn == h0) ? h1 : h0;
    }
}